// Round 2
// baseline (1619.287 us; speedup 1.0000x reference)
//
#include <hip/hip_runtime.h>
#include <hip/hip_bf16.h>

typedef _Float16 half8 __attribute__((ext_vector_type(8)));
typedef float floatx4 __attribute__((ext_vector_type(4)));

#define N_NODES 50000
#define N_EDGES 1600000
#define FX 128
#define FE 64
#define KIN 192   // FX + FE
#define H   128

// ---------------------------------------------------------------------------
// Edge kernel: h = relu([x[col]||ea] @ W1a + b1a) @ W1b + b1b ; scatter-add
// Block: 256 thr = 4 waves; wave (rw,cw): rows rw*16..+16 of a 32-edge tile,
// cols cw*64..+64. Weights live in registers as MFMA B-fragments.
// ---------------------------------------------------------------------------
__global__ __launch_bounds__(256, 4)
void edge_kernel(const float* __restrict__ x,
                 const int*   __restrict__ ei,
                 const float* __restrict__ ea,
                 const float* __restrict__ W1a, const float* __restrict__ b1a,
                 const float* __restrict__ W1b, const float* __restrict__ b1b,
                 float* __restrict__ sums, float* __restrict__ cnt)
{
    __shared__ _Float16 in_lds[32 * KIN];   // 12 KB, XOR-swizzled rows (384B row)
    __shared__ _Float16 h1_lds[32 * H];     // 8 KB,  XOR-swizzled rows (256B row)
    __shared__ int rows_s[32];
    __shared__ int cols_s[32];

    const int tid  = threadIdx.x;
    const int lane = tid & 63;
    const int wid  = tid >> 6;
    const int rw   = wid & 1;     // row-group of 16 edges
    const int cw   = wid >> 1;    // col-group of 64 cols
    const int l15  = lane & 15;
    const int hi   = lane >> 4;

    // ---- load weight fragments into registers (consistent k-bijection) ----
    half8 w1a_f[6][4];
    half8 w1b_f[4][4];
    float b1a_r[4], b1b_r[4];
    #pragma unroll
    for (int ct = 0; ct < 4; ++ct) {
        const int colg = cw * 64 + ct * 16 + l15;
        b1a_r[ct] = b1a[colg];
        b1b_r[ct] = b1b[colg];
        #pragma unroll
        for (int kt = 0; kt < 6; ++kt) {
            half8 f;
            #pragma unroll
            for (int j = 0; j < 8; ++j)
                f[j] = (_Float16)W1a[(kt * 32 + hi * 8 + j) * H + colg];
            w1a_f[kt][ct] = f;
        }
        #pragma unroll
        for (int kt = 0; kt < 4; ++kt) {
            half8 f;
            #pragma unroll
            for (int j = 0; j < 8; ++j)
                f[j] = (_Float16)W1b[(kt * 32 + hi * 8 + j) * H + colg];
            w1b_f[kt][ct] = f;
        }
    }

    const int ntiles = N_EDGES / 32;   // exactly 50000
    for (int tile = blockIdx.x; tile < ntiles; tile += gridDim.x) {
        const int ebase = tile * 32;

        if (tid < 32) {
            const int r = ei[ebase + tid];
            const int c = ei[N_EDGES + ebase + tid];
            rows_s[tid] = r;
            cols_s[tid] = c;
            unsafeAtomicAdd(&cnt[r], 1.0f);
        }
        __syncthreads();

        // ---- stage [x[col] || ea] as f16, 32 rows x 24 chunks of 16B ----
        for (int idx = tid; idx < 32 * 24; idx += 256) {
            const int r = idx / 24;
            const int c = idx % 24;
            const float* src = (c < 16)
                ? x  + (size_t)cols_s[r] * FX + c * 8
                : ea + (size_t)(ebase + r) * FE + (c - 16) * 8;
            const float4 v0 = *(const float4*)(src);
            const float4 v1 = *(const float4*)(src + 4);
            half8 h;
            h[0] = (_Float16)v0.x; h[1] = (_Float16)v0.y;
            h[2] = (_Float16)v0.z; h[3] = (_Float16)v0.w;
            h[4] = (_Float16)v1.x; h[5] = (_Float16)v1.y;
            h[6] = (_Float16)v1.z; h[7] = (_Float16)v1.w;
            const int byte = (r * (KIN * 2) + c * 16) ^ ((r & 7) << 4);
            *(half8*)((char*)in_lds + byte) = h;
        }
        __syncthreads();

        // ---- layer 1: [32,192] @ [192,128] ----
        floatx4 acc1[4];
        #pragma unroll
        for (int ct = 0; ct < 4; ++ct) acc1[ct] = (floatx4){0.f, 0.f, 0.f, 0.f};
        #pragma unroll
        for (int kt = 0; kt < 6; ++kt) {
            const int r = rw * 16 + l15;
            const int byte = (r * (KIN * 2) + kt * 64 + hi * 16) ^ ((r & 7) << 4);
            const half8 a = *(const half8*)((const char*)in_lds + byte);
            #pragma unroll
            for (int ct = 0; ct < 4; ++ct)
                acc1[ct] = __builtin_amdgcn_mfma_f32_16x16x32_f16(a, w1a_f[kt][ct], acc1[ct], 0, 0, 0);
        }
        // bias + relu -> h1 (f16 in LDS)
        #pragma unroll
        for (int ct = 0; ct < 4; ++ct) {
            const int col = cw * 64 + ct * 16 + l15;
            #pragma unroll
            for (int j = 0; j < 4; ++j) {
                const int r = rw * 16 + hi * 4 + j;
                float v = acc1[ct][j] + b1a_r[ct];
                v = v > 0.f ? v : 0.f;
                const int byte = (r * (H * 2) + col * 2) ^ ((r & 7) << 4);
                *(_Float16*)((char*)h1_lds + byte) = (_Float16)v;
            }
        }
        __syncthreads();

        // ---- layer 2: [32,128] @ [128,128] ----
        floatx4 acc2[4];
        #pragma unroll
        for (int ct = 0; ct < 4; ++ct) acc2[ct] = (floatx4){0.f, 0.f, 0.f, 0.f};
        #pragma unroll
        for (int kt = 0; kt < 4; ++kt) {
            const int r = rw * 16 + l15;
            const int byte = (r * (H * 2) + kt * 64 + hi * 16) ^ ((r & 7) << 4);
            const half8 a = *(const half8*)((const char*)h1_lds + byte);
            #pragma unroll
            for (int ct = 0; ct < 4; ++ct)
                acc2[ct] = __builtin_amdgcn_mfma_f32_16x16x32_f16(a, w1b_f[kt][ct], acc2[ct], 0, 0, 0);
        }
        // ---- scatter-add (+b1b) into sums, count handled above ----
        #pragma unroll
        for (int ct = 0; ct < 4; ++ct) {
            const int col = cw * 64 + ct * 16 + l15;
            #pragma unroll
            for (int j = 0; j < 4; ++j) {
                const int rl = rw * 16 + hi * 4 + j;
                const float v = acc2[ct][j] + b1b_r[ct];
                unsafeAtomicAdd(&sums[(size_t)rows_s[rl] * H + col], v);
            }
        }
        __syncthreads();
    }
}

// ---------------------------------------------------------------------------
// Node kernel: out = relu([x||sums/cnt] @ W2a + b2a) @ W2b + b2b
// sums lives in d_out; read rows then overwrite in place (row-local).
// Block: 4 waves, each owns 32 cols; 16 rows per tile (50000 = 16*3125).
// ---------------------------------------------------------------------------
__global__ __launch_bounds__(256, 4)
void node_kernel(const float* __restrict__ x,
                 const float* __restrict__ cnt,
                 const float* __restrict__ W2a, const float* __restrict__ b2a,
                 const float* __restrict__ W2b, const float* __restrict__ b2b,
                 float* __restrict__ out)   // holds sums on entry
{
    __shared__ _Float16 z_lds[16 * 256];   // 8 KB (512B rows)
    __shared__ _Float16 h1_lds[16 * H];    // 4 KB (256B rows)

    const int tid  = threadIdx.x;
    const int lane = tid & 63;
    const int cw   = tid >> 6;       // 4 col-groups of 32
    const int l15  = lane & 15;
    const int hi   = lane >> 4;

    half8 w2a_f[8][2];
    half8 w2b_f[4][2];
    float b2a_r[2], b2b_r[2];
    #pragma unroll
    for (int ct = 0; ct < 2; ++ct) {
        const int colg = cw * 32 + ct * 16 + l15;
        b2a_r[ct] = b2a[colg];
        b2b_r[ct] = b2b[colg];
        #pragma unroll
        for (int kt = 0; kt < 8; ++kt) {
            half8 f;
            #pragma unroll
            for (int j = 0; j < 8; ++j)
                f[j] = (_Float16)W2a[(kt * 32 + hi * 8 + j) * H + colg];
            w2a_f[kt][ct] = f;
        }
        #pragma unroll
        for (int kt = 0; kt < 4; ++kt) {
            half8 f;
            #pragma unroll
            for (int j = 0; j < 8; ++j)
                f[j] = (_Float16)W2b[(kt * 32 + hi * 8 + j) * H + colg];
            w2b_f[kt][ct] = f;
        }
    }

    const int ntiles = N_NODES / 16;   // exactly 3125
    for (int tile = blockIdx.x; tile < ntiles; tile += gridDim.x) {
        const int base = tile * 16;

        // ---- stage z = [x || sums/cnt] as f16: 16 rows x 32 chunks ----
        for (int idx = tid; idx < 16 * 32; idx += 256) {
            const int r = idx >> 5;
            const int c = idx & 31;
            const int rg = base + r;
            half8 h;
            if (c < 16) {
                const float* src = x + (size_t)rg * FX + c * 8;
                const float4 v0 = *(const float4*)(src);
                const float4 v1 = *(const float4*)(src + 4);
                h[0] = (_Float16)v0.x; h[1] = (_Float16)v0.y;
                h[2] = (_Float16)v0.z; h[3] = (_Float16)v0.w;
                h[4] = (_Float16)v1.x; h[5] = (_Float16)v1.y;
                h[6] = (_Float16)v1.z; h[7] = (_Float16)v1.w;
            } else {
                const float ic = 1.0f / fmaxf(cnt[rg], 1.0f);
                const float* src = out + (size_t)rg * H + (c - 16) * 8;
                const float4 v0 = *(const float4*)(src);
                const float4 v1 = *(const float4*)(src + 4);
                h[0] = (_Float16)(v0.x * ic); h[1] = (_Float16)(v0.y * ic);
                h[2] = (_Float16)(v0.z * ic); h[3] = (_Float16)(v0.w * ic);
                h[4] = (_Float16)(v1.x * ic); h[5] = (_Float16)(v1.y * ic);
                h[6] = (_Float16)(v1.z * ic); h[7] = (_Float16)(v1.w * ic);
            }
            const int byte = (r * 512 + c * 16) ^ ((r & 7) << 4);
            *(half8*)((char*)z_lds + byte) = h;
        }
        __syncthreads();

        // ---- layer 1: K=256 ----
        floatx4 acc1[2];
        #pragma unroll
        for (int ct = 0; ct < 2; ++ct) acc1[ct] = (floatx4){0.f, 0.f, 0.f, 0.f};
        #pragma unroll
        for (int kt = 0; kt < 8; ++kt) {
            const int byte = (l15 * 512 + kt * 64 + hi * 16) ^ ((l15 & 7) << 4);
            const half8 a = *(const half8*)((const char*)z_lds + byte);
            #pragma unroll
            for (int ct = 0; ct < 2; ++ct)
                acc1[ct] = __builtin_amdgcn_mfma_f32_16x16x32_f16(a, w2a_f[kt][ct], acc1[ct], 0, 0, 0);
        }
        #pragma unroll
        for (int ct = 0; ct < 2; ++ct) {
            const int col = cw * 32 + ct * 16 + l15;
            #pragma unroll
            for (int j = 0; j < 4; ++j) {
                const int r = hi * 4 + j;
                float v = acc1[ct][j] + b2a_r[ct];
                v = v > 0.f ? v : 0.f;
                const int byte = (r * (H * 2) + col * 2) ^ ((r & 7) << 4);
                *(_Float16*)((char*)h1_lds + byte) = (_Float16)v;
            }
        }
        __syncthreads();

        // ---- layer 2: K=128 ----
        floatx4 acc2[2];
        #pragma unroll
        for (int ct = 0; ct < 2; ++ct) acc2[ct] = (floatx4){0.f, 0.f, 0.f, 0.f};
        #pragma unroll
        for (int kt = 0; kt < 4; ++kt) {
            const int byte = (l15 * (H * 2) + kt * 64 + hi * 16) ^ ((l15 & 7) << 4);
            const half8 a = *(const half8*)((const char*)h1_lds + byte);
            #pragma unroll
            for (int ct = 0; ct < 2; ++ct)
                acc2[ct] = __builtin_amdgcn_mfma_f32_16x16x32_f16(a, w2b_f[kt][ct], acc2[ct], 0, 0, 0);
        }
        // ---- write out (overwrites sums rows of this tile only) ----
        #pragma unroll
        for (int ct = 0; ct < 2; ++ct) {
            const int col = cw * 32 + ct * 16 + l15;
            #pragma unroll
            for (int j = 0; j < 4; ++j) {
                const int rg = base + hi * 4 + j;
                out[(size_t)rg * H + col] = acc2[ct][j] + b2b_r[ct];
            }
        }
        __syncthreads();
    }
}

extern "C" void kernel_launch(void* const* d_in, const int* in_sizes, int n_in,
                              void* d_out, int out_size, void* d_ws, size_t ws_size,
                              hipStream_t stream)
{
    const float* x   = (const float*)d_in[0];
    const int*   ei  = (const int*)  d_in[1];
    const float* ea  = (const float*)d_in[2];
    // d_in[3] = u (unused), d_in[4] = batch (unused)
    const float* W1a = (const float*)d_in[5];
    const float* b1a = (const float*)d_in[6];
    const float* W1b = (const float*)d_in[7];
    const float* b1b = (const float*)d_in[8];
    const float* W2a = (const float*)d_in[9];
    const float* b2a = (const float*)d_in[10];
    const float* W2b = (const float*)d_in[11];
    const float* b2b = (const float*)d_in[12];

    float* out  = (float*)d_out;          // doubles as `sums` accumulator
    float* cnt  = (float*)d_ws;           // N floats

    hipMemsetAsync(out, 0, (size_t)N_NODES * H * sizeof(float), stream);
    hipMemsetAsync(cnt, 0, (size_t)N_NODES * sizeof(float), stream);

    edge_kernel<<<dim3(2048), dim3(256), 0, stream>>>(x, ei, ea, W1a, b1a, W1b, b1b, out, cnt);
    node_kernel<<<dim3(1024), dim3(256), 0, stream>>>(x, cnt, W2a, b2a, W2b, b2b, out);
}

// Round 3
// 1211.818 us; speedup vs baseline: 1.3362x; 1.3362x over previous
//
#include <hip/hip_runtime.h>
#include <hip/hip_bf16.h>

typedef _Float16 half8 __attribute__((ext_vector_type(8)));
typedef float floatx4 __attribute__((ext_vector_type(4)));

#define N_NODES 50000
#define N_EDGES 1600000
#define FX 128
#define FE 64
#define KIN 192   // FX + FE
#define H   128

// ---------------------------------------------------------------------------
// Edge kernel: h = relu([x[col]||ea] @ W1a + b1a) @ W1b + b1b ; scatter-add.
// Block: 512 thr = 8 waves. Tile = 16 edges x 128 cols; each wave owns 16
// cols (wid*16..+16) and all 16 rows. Weights: 40 VGPRs/wave -> <=128 tier,
// 16 waves/CU (2 blocks/CU) without spilling.
// ---------------------------------------------------------------------------
__global__ __launch_bounds__(512, 4)
void edge_kernel(const float* __restrict__ x,
                 const int*   __restrict__ ei,
                 const float* __restrict__ ea,
                 const float* __restrict__ W1a, const float* __restrict__ b1a,
                 const float* __restrict__ W1b, const float* __restrict__ b1b,
                 float* __restrict__ sums, float* __restrict__ cnt)
{
    __shared__ _Float16 in_lds[16 * KIN];   // 6 KB, rows 384B, XOR-swizzled
    __shared__ _Float16 h1_lds[16 * H];     // 4 KB, rows 256B, XOR-swizzled
    __shared__ int rows_s[16];
    __shared__ int cols_s[16];

    const int tid  = threadIdx.x;
    const int lane = tid & 63;
    const int wid  = tid >> 6;    // 0..7 -> col group of 16
    const int l15  = lane & 15;
    const int hi   = lane >> 4;

    // ---- weight fragments in registers (k = kt*32 + hi*8 + j bijection) ----
    half8 w1a_f[6];
    half8 w1b_f[4];
    const int colg = wid * 16 + l15;
    const float b1a_r = b1a[colg];
    const float b1b_r = b1b[colg];
    #pragma unroll
    for (int kt = 0; kt < 6; ++kt) {
        half8 f;
        #pragma unroll
        for (int j = 0; j < 8; ++j)
            f[j] = (_Float16)W1a[(kt * 32 + hi * 8 + j) * H + colg];
        w1a_f[kt] = f;
    }
    #pragma unroll
    for (int kt = 0; kt < 4; ++kt) {
        half8 f;
        #pragma unroll
        for (int j = 0; j < 8; ++j)
            f[j] = (_Float16)W1b[(kt * 32 + hi * 8 + j) * H + colg];
        w1b_f[kt] = f;
    }

    const int ntiles = N_EDGES / 16;   // exactly 100000
    for (int tile = blockIdx.x; tile < ntiles; tile += gridDim.x) {
        const int ebase = tile * 16;

        if (tid < 16) {
            const int r = ei[ebase + tid];
            const int c = ei[N_EDGES + ebase + tid];
            rows_s[tid] = r;
            cols_s[tid] = c;
            unsafeAtomicAdd(&cnt[r], 1.0f);
        }
        __syncthreads();

        // ---- stage [x[col] || ea] as f16 ----
        // x part: 16 rows x 16 chunks (256); ea part: 16 rows x 8 chunks (128)
        if (tid < 384) {
            const float* src;
            int r, byte;
            if (tid < 256) {
                r = tid >> 4;
                const int c = tid & 15;
                src  = x + (size_t)cols_s[r] * FX + c * 8;
                byte = (r * (KIN * 2) + c * 16) ^ ((r & 7) << 4);
            } else {
                const int i = tid - 256;
                r = i >> 3;
                const int c = i & 7;
                src  = ea + (size_t)(ebase + r) * FE + c * 8;
                byte = (r * (KIN * 2) + 256 + c * 16) ^ ((r & 7) << 4);
            }
            const float4 v0 = *(const float4*)(src);
            const float4 v1 = *(const float4*)(src + 4);
            half8 h;
            h[0] = (_Float16)v0.x; h[1] = (_Float16)v0.y;
            h[2] = (_Float16)v0.z; h[3] = (_Float16)v0.w;
            h[4] = (_Float16)v1.x; h[5] = (_Float16)v1.y;
            h[6] = (_Float16)v1.z; h[7] = (_Float16)v1.w;
            *(half8*)((char*)in_lds + byte) = h;
        }
        __syncthreads();

        // ---- layer 1: [16,192] @ [192,16] per wave ----
        floatx4 acc1 = (floatx4){0.f, 0.f, 0.f, 0.f};
        #pragma unroll
        for (int kt = 0; kt < 6; ++kt) {
            const int byte = (l15 * (KIN * 2) + kt * 64 + hi * 16) ^ ((l15 & 7) << 4);
            const half8 a = *(const half8*)((const char*)in_lds + byte);
            acc1 = __builtin_amdgcn_mfma_f32_16x16x32_f16(a, w1a_f[kt], acc1, 0, 0, 0);
        }
        // bias + relu -> h1 (f16 in LDS)
        #pragma unroll
        for (int j = 0; j < 4; ++j) {
            const int r = hi * 4 + j;
            float v = acc1[j] + b1a_r;
            v = v > 0.f ? v : 0.f;
            const int byte = (r * (H * 2) + colg * 2) ^ ((r & 7) << 4);
            *(_Float16*)((char*)h1_lds + byte) = (_Float16)v;
        }
        __syncthreads();

        // ---- layer 2: [16,128] @ [128,16] per wave ----
        floatx4 acc2 = (floatx4){0.f, 0.f, 0.f, 0.f};
        #pragma unroll
        for (int kt = 0; kt < 4; ++kt) {
            const int byte = (l15 * (H * 2) + kt * 64 + hi * 16) ^ ((l15 & 7) << 4);
            const half8 a = *(const half8*)((const char*)h1_lds + byte);
            acc2 = __builtin_amdgcn_mfma_f32_16x16x32_f16(a, w1b_f[kt], acc2, 0, 0, 0);
        }
        // ---- scatter-add (+b1b) into sums ----
        #pragma unroll
        for (int j = 0; j < 4; ++j) {
            const int rl = hi * 4 + j;
            const float v = acc2[j] + b1b_r;
            unsafeAtomicAdd(&sums[(size_t)rows_s[rl] * H + colg], v);
        }
        __syncthreads();
    }
}

// ---------------------------------------------------------------------------
// Node kernel: out = relu([x||sums/cnt] @ W2a + b2a) @ W2b + b2b.
// sums lives in d_out; each 16-row tile reads its own rows then overwrites
// them (row-local, no cross-tile hazard). Block 512 = 8 waves, wave owns
// 16 cols; ~48 VGPRs of weights.
// ---------------------------------------------------------------------------
__global__ __launch_bounds__(512, 4)
void node_kernel(const float* __restrict__ x,
                 const float* __restrict__ cnt,
                 const float* __restrict__ W2a, const float* __restrict__ b2a,
                 const float* __restrict__ W2b, const float* __restrict__ b2b,
                 float* __restrict__ out)   // holds sums on entry
{
    __shared__ _Float16 z_lds[16 * 256];   // 8 KB, rows 512B, XOR-swizzled
    __shared__ _Float16 h1_lds[16 * H];    // 4 KB

    const int tid  = threadIdx.x;
    const int lane = tid & 63;
    const int wid  = tid >> 6;
    const int l15  = lane & 15;
    const int hi   = lane >> 4;

    half8 w2a_f[8];
    half8 w2b_f[4];
    const int colg = wid * 16 + l15;
    const float b2a_r = b2a[colg];
    const float b2b_r = b2b[colg];
    #pragma unroll
    for (int kt = 0; kt < 8; ++kt) {
        half8 f;
        #pragma unroll
        for (int j = 0; j < 8; ++j)
            f[j] = (_Float16)W2a[(kt * 32 + hi * 8 + j) * H + colg];
        w2a_f[kt] = f;
    }
    #pragma unroll
    for (int kt = 0; kt < 4; ++kt) {
        half8 f;
        #pragma unroll
        for (int j = 0; j < 8; ++j)
            f[j] = (_Float16)W2b[(kt * 32 + hi * 8 + j) * H + colg];
        w2b_f[kt] = f;
    }

    const int ntiles = N_NODES / 16;   // exactly 3125
    for (int tile = blockIdx.x; tile < ntiles; tile += gridDim.x) {
        const int base = tile * 16;

        // ---- stage z = [x || sums/cnt] as f16: 16 rows x 32 chunks ----
        {
            const int r = tid >> 5;
            const int c = tid & 31;
            const int rg = base + r;
            half8 h;
            if (c < 16) {
                const float* src = x + (size_t)rg * FX + c * 8;
                const float4 v0 = *(const float4*)(src);
                const float4 v1 = *(const float4*)(src + 4);
                h[0] = (_Float16)v0.x; h[1] = (_Float16)v0.y;
                h[2] = (_Float16)v0.z; h[3] = (_Float16)v0.w;
                h[4] = (_Float16)v1.x; h[5] = (_Float16)v1.y;
                h[6] = (_Float16)v1.z; h[7] = (_Float16)v1.w;
            } else {
                const float ic = 1.0f / fmaxf(cnt[rg], 1.0f);
                const float* src = out + (size_t)rg * H + (c - 16) * 8;
                const float4 v0 = *(const float4*)(src);
                const float4 v1 = *(const float4*)(src + 4);
                h[0] = (_Float16)(v0.x * ic); h[1] = (_Float16)(v0.y * ic);
                h[2] = (_Float16)(v0.z * ic); h[3] = (_Float16)(v0.w * ic);
                h[4] = (_Float16)(v1.x * ic); h[5] = (_Float16)(v1.y * ic);
                h[6] = (_Float16)(v1.z * ic); h[7] = (_Float16)(v1.w * ic);
            }
            const int byte = (r * 512 + c * 16) ^ ((r & 7) << 4);
            *(half8*)((char*)z_lds + byte) = h;
        }
        __syncthreads();

        // ---- layer 1: K=256 ----
        floatx4 acc1 = (floatx4){0.f, 0.f, 0.f, 0.f};
        #pragma unroll
        for (int kt = 0; kt < 8; ++kt) {
            const int byte = (l15 * 512 + kt * 64 + hi * 16) ^ ((l15 & 7) << 4);
            const half8 a = *(const half8*)((const char*)z_lds + byte);
            acc1 = __builtin_amdgcn_mfma_f32_16x16x32_f16(a, w2a_f[kt], acc1, 0, 0, 0);
        }
        #pragma unroll
        for (int j = 0; j < 4; ++j) {
            const int r = hi * 4 + j;
            float v = acc1[j] + b2a_r;
            v = v > 0.f ? v : 0.f;
            const int byte = (r * (H * 2) + colg * 2) ^ ((r & 7) << 4);
            *(_Float16*)((char*)h1_lds + byte) = (_Float16)v;
        }
        __syncthreads();

        // ---- layer 2: K=128 ----
        floatx4 acc2 = (floatx4){0.f, 0.f, 0.f, 0.f};
        #pragma unroll
        for (int kt = 0; kt < 4; ++kt) {
            const int byte = (l15 * (H * 2) + kt * 64 + hi * 16) ^ ((l15 & 7) << 4);
            const half8 a = *(const half8*)((const char*)h1_lds + byte);
            acc2 = __builtin_amdgcn_mfma_f32_16x16x32_f16(a, w2b_f[kt], acc2, 0, 0, 0);
        }
        // ---- write out (overwrites this tile's sums rows only) ----
        #pragma unroll
        for (int j = 0; j < 4; ++j) {
            const int rg = base + hi * 4 + j;
            out[(size_t)rg * H + colg] = acc2[j] + b2b_r;
        }
        __syncthreads();
    }
}

extern "C" void kernel_launch(void* const* d_in, const int* in_sizes, int n_in,
                              void* d_out, int out_size, void* d_ws, size_t ws_size,
                              hipStream_t stream)
{
    const float* x   = (const float*)d_in[0];
    const int*   ei  = (const int*)  d_in[1];
    const float* ea  = (const float*)d_in[2];
    // d_in[3] = u (unused), d_in[4] = batch (unused)
    const float* W1a = (const float*)d_in[5];
    const float* b1a = (const float*)d_in[6];
    const float* W1b = (const float*)d_in[7];
    const float* b1b = (const float*)d_in[8];
    const float* W2a = (const float*)d_in[9];
    const float* b2a = (const float*)d_in[10];
    const float* W2b = (const float*)d_in[11];
    const float* b2b = (const float*)d_in[12];

    float* out  = (float*)d_out;          // doubles as `sums` accumulator
    float* cnt  = (float*)d_ws;           // N floats

    hipMemsetAsync(out, 0, (size_t)N_NODES * H * sizeof(float), stream);
    hipMemsetAsync(cnt, 0, (size_t)N_NODES * sizeof(float), stream);

    edge_kernel<<<dim3(2048), dim3(512), 0, stream>>>(x, ei, ea, W1a, b1a, W1b, b1b, out, cnt);
    node_kernel<<<dim3(2048), dim3(512), 0, stream>>>(x, cnt, W2a, b2a, W2b, b2b, out);
}